// Round 1
// baseline (1130.395 us; speedup 1.0000x reference)
//
#include <hip/hip_runtime.h>
#include <math.h>

#define NSRC 8192
#define NTGT 8192
#define DIM 64

// ---------------------------------------------------------------------------
// helpers
// ---------------------------------------------------------------------------
__device__ __forceinline__ float wave_reduce_sum(float x) {
#pragma unroll
  for (int off = 32; off > 0; off >>= 1) x += __shfl_down(x, off, 64);
  return x;
}

// ---------------------------------------------------------------------------
// kernel 1: squared norms of source rows and target rows
//   s2[i] = sum_k S[i][k]^2 ; t2[j] = sum_k T[j][k]^2
// ---------------------------------------------------------------------------
__global__ __launch_bounds__(256) void norms_k(const float* __restrict__ S,
                                               const float* __restrict__ T,
                                               float* __restrict__ s2,
                                               float* __restrict__ t2) {
  int i = blockIdx.x * 256 + threadIdx.x;
  if (i >= NSRC + NTGT) return;
  const float* base = (i < NSRC) ? (S + (size_t)i * DIM)
                                 : (T + (size_t)(i - NSRC) * DIM);
  const float4* p = (const float4*)base;
  float a = 0.f;
#pragma unroll
  for (int k = 0; k < DIM / 4; ++k) {
    float4 v = p[k];
    a += v.x * v.x + v.y * v.y + v.z * v.z + v.w * v.w;
  }
  if (i < NSRC) s2[i] = a;
  else          t2[i - NSRC] = a;
}

// ---------------------------------------------------------------------------
// kernel 2: per-call init. c[]=0 (colsum accumulator), v=1 (initial scaling).
// Must run every call: ws/d_out are poisoned once before timed replays.
// ---------------------------------------------------------------------------
__global__ __launch_bounds__(256) void init_k(float* __restrict__ c,
                                              float* __restrict__ v_out) {
  int i = blockIdx.x * 256 + threadIdx.x;
  if (i < NTGT) {
    c[i] = 0.f;
    v_out[i] = 1.f;
  }
}

// ---------------------------------------------------------------------------
// kernel 3: build K = exp(-cost/eps) into the coupling region of d_out.
// cost_ij = sqrt(max(s2_i + t2_j - 2*dot(S_i,T_j), 0))
// Tile: 64 rows x 128 cols per block, 256 threads, each 4x8 micro-tile.
// LDS padded to 68 floats/row: float4 LDS IO stays 16B aligned, and the
// strided (r = ty+16a, c = tx+16b) mapping keeps bank conflicts ~2-way.
// ---------------------------------------------------------------------------
#define BM 64
#define BN 128
__global__ __launch_bounds__(256) void kbuild_k(const float* __restrict__ S,
                                                const float* __restrict__ T,
                                                const float* __restrict__ s2,
                                                const float* __restrict__ t2,
                                                float* __restrict__ K) {
  __shared__ float sT[BM][68];
  __shared__ float tT[BN][68];
  const int bn = blockIdx.x * BN;
  const int bm = blockIdx.y * BM;
  const int tid = threadIdx.x;

  // stage S tile (64x64 floats = 1024 float4)
  {
    const float4* sg = (const float4*)(S + (size_t)bm * DIM);
#pragma unroll
    for (int k = 0; k < 4; ++k) {
      int f = tid + 256 * k;
      int row = f >> 4, c4 = f & 15;
      *(float4*)&sT[row][c4 * 4] = sg[f];
    }
    const float4* tg = (const float4*)(T + (size_t)bn * DIM);
#pragma unroll
    for (int k = 0; k < 8; ++k) {
      int f = tid + 256 * k;
      int row = f >> 4, c4 = f & 15;
      *(float4*)&tT[row][c4 * 4] = tg[f];
    }
  }
  __syncthreads();

  const int tx = tid & 15;   // column group: cols tx + 16*b
  const int ty = tid >> 4;   // row group:    rows ty + 16*a

  float acc[4][8];
#pragma unroll
  for (int a = 0; a < 4; ++a)
#pragma unroll
    for (int b = 0; b < 8; ++b) acc[a][b] = 0.f;

  for (int k = 0; k < DIM; k += 4) {
    float4 sr[4], tr[8];
#pragma unroll
    for (int a = 0; a < 4; ++a) sr[a] = *(float4*)&sT[ty + 16 * a][k];
#pragma unroll
    for (int b = 0; b < 8; ++b) tr[b] = *(float4*)&tT[tx + 16 * b][k];
#pragma unroll
    for (int a = 0; a < 4; ++a)
#pragma unroll
      for (int b = 0; b < 8; ++b) {
        acc[a][b] += sr[a].x * tr[b].x;
        acc[a][b] += sr[a].y * tr[b].y;
        acc[a][b] += sr[a].z * tr[b].z;
        acc[a][b] += sr[a].w * tr[b].w;
      }
  }

#pragma unroll
  for (int a = 0; a < 4; ++a) {
    int gi = bm + ty + 16 * a;
    float s2v = s2[gi];
#pragma unroll
    for (int b = 0; b < 8; ++b) {
      int gj = bn + tx + 16 * b;
      float sq = s2v + t2[gj] - 2.f * acc[a][b];
      float cost = sqrtf(fmaxf(sq, 0.f));
      K[(size_t)gi * NTGT + gj] = __expf(-10.f * cost);  // 1/eps = 10
    }
  }
}

// ---------------------------------------------------------------------------
// kernel 4: u_i = sw / ((K v)_i + stab). One wave per row.
// ---------------------------------------------------------------------------
__global__ __launch_bounds__(256) void rowsum_k(const float* __restrict__ K,
                                                const float* __restrict__ v,
                                                float* __restrict__ u_out) {
  int row = (blockIdx.x * 256 + threadIdx.x) >> 6;
  int lane = threadIdx.x & 63;
  const float4* r4 = (const float4*)(K + (size_t)row * NTGT);
  const float4* v4 = (const float4*)v;
  float a = 0.f;
#pragma unroll 4
  for (int j = lane; j < NTGT / 4; j += 64) {
    float4 k4 = r4[j];
    float4 vv = v4[j];
    a += k4.x * vv.x + k4.y * vv.y + k4.z * vv.z + k4.w * vv.w;
  }
  a = wave_reduce_sum(a);
  if (lane == 0) u_out[row] = (1.0f / NSRC) / (a + 1e-8f);
}

// ---------------------------------------------------------------------------
// kernel 5: c_j += sum_i K_ij * u_i over a 64-row chunk (atomic into ws c).
// grid = (8 col-stripes of 1024, 128 row-chunks of 64)
// ---------------------------------------------------------------------------
__global__ __launch_bounds__(256) void colsum_k(const float* __restrict__ K,
                                                const float* __restrict__ u,
                                                float* __restrict__ c) {
  int j = blockIdx.x * 1024 + threadIdx.x * 4;
  int i0 = blockIdx.y * 64;
  float a0 = 0.f, a1 = 0.f, a2 = 0.f, a3 = 0.f;
#pragma unroll 8
  for (int i = i0; i < i0 + 64; ++i) {
    float ui = u[i];
    float4 k4 = *(const float4*)(K + (size_t)i * NTGT + j);
    a0 += k4.x * ui; a1 += k4.y * ui; a2 += k4.z * ui; a3 += k4.w * ui;
  }
  atomicAdd(&c[j + 0], a0);
  atomicAdd(&c[j + 1], a1);
  atomicAdd(&c[j + 2], a2);
  atomicAdd(&c[j + 3], a3);
}

// ---------------------------------------------------------------------------
// kernel 6: v_j = tw / (c_j + stab); reset c_j = 0 for next iteration.
// ---------------------------------------------------------------------------
__global__ __launch_bounds__(256) void finishv_k(float* __restrict__ c,
                                                 float* __restrict__ v_out) {
  int j = blockIdx.x * 256 + threadIdx.x;
  v_out[j] = (1.0f / NTGT) / (c[j] + 1e-8f);
  c[j] = 0.f;
}

// ---------------------------------------------------------------------------
// kernel 7: coupling_ij = u_i * K_ij * v_j written in place over K;
// accumulate sum(coupling * cost) with cost = -eps*ln(K). Per-block partial
// (deterministic), no atomics.
// ---------------------------------------------------------------------------
__global__ __launch_bounds__(256) void coupling_k(float* __restrict__ K,
                                                  const float* __restrict__ u,
                                                  const float* __restrict__ v,
                                                  float* __restrict__ partials) {
  __shared__ float red[4];
  size_t t0 = (size_t)blockIdx.x * 2048 + threadIdx.x;  // float4 index
  float part = 0.f;
#pragma unroll
  for (int s = 0; s < 8; ++s) {
    size_t f4 = t0 + (size_t)s * 256;
    size_t base = f4 * 4;
    int i = (int)(base >> 13);   // /8192
    int j = (int)(base & 8191);
    float4 k4 = *(float4*)(K + base);
    float ui = u[i];
    float4 vv = *(const float4*)(v + j);
    float c0 = ui * k4.x * vv.x;
    float c1 = ui * k4.y * vv.y;
    float c2 = ui * k4.z * vv.z;
    float c3 = ui * k4.w * vv.w;
    // cost = -0.1*log(K); accumulate c*log(K), scale by -0.1 at the end
    part += c0 * __logf(k4.x) + c1 * __logf(k4.y) +
            c2 * __logf(k4.z) + c3 * __logf(k4.w);
    *(float4*)(K + base) = make_float4(c0, c1, c2, c3);
  }
  part = wave_reduce_sum(part);
  int wid = threadIdx.x >> 6, lane = threadIdx.x & 63;
  if (lane == 0) red[wid] = part;
  __syncthreads();
  if (threadIdx.x == 0)
    partials[blockIdx.x] = red[0] + red[1] + red[2] + red[3];
}

// ---------------------------------------------------------------------------
// kernel 8: dist = -eps * sum(partials) / (ns*nt)
// ---------------------------------------------------------------------------
__global__ __launch_bounds__(256) void finalize_k(const float* __restrict__ partials,
                                                  float* __restrict__ out) {
  __shared__ float red[4];
  float a = 0.f;
  for (int i = threadIdx.x; i < 8192; i += 256) a += partials[i];
  a = wave_reduce_sum(a);
  int wid = threadIdx.x >> 6, lane = threadIdx.x & 63;
  if (lane == 0) red[wid] = a;
  __syncthreads();
  if (threadIdx.x == 0)
    out[0] = (red[0] + red[1] + red[2] + red[3]) *
             (-0.1f / ((float)NSRC * (float)NTGT));
}

// ---------------------------------------------------------------------------
extern "C" void kernel_launch(void* const* d_in, const int* in_sizes, int n_in,
                              void* d_out, int out_size, void* d_ws, size_t ws_size,
                              hipStream_t stream) {
  const float* S = (const float*)d_in[0];
  const float* T = (const float*)d_in[1];
  float* out = (float*)d_out;

  // output layout: [dist(1)][coupling(64M)][u(8192)][v(8192)]
  float* K    = out + 1;                       // K lives where coupling goes
  float* u    = out + 1 + (size_t)NSRC * NTGT;
  float* vv   = u + NSRC;

  // ws layout (floats): c[8192] | s2[8192] | t2[8192] | partials[8192]
  float* wsf      = (float*)d_ws;
  float* c        = wsf;
  float* s2       = wsf + 8192;
  float* t2       = wsf + 16384;
  float* partials = wsf + 24576;

  norms_k<<<(NSRC + NTGT + 255) / 256, 256, 0, stream>>>(S, T, s2, t2);
  init_k<<<NTGT / 256, 256, 0, stream>>>(c, vv);
  kbuild_k<<<dim3(NTGT / BN, NSRC / BM), 256, 0, stream>>>(S, T, s2, t2, K);

  for (int it = 0; it < 10; ++it) {
    rowsum_k<<<NSRC * 64 / 256, 256, 0, stream>>>(K, vv, u);
    colsum_k<<<dim3(8, 128), 256, 0, stream>>>(K, u, c);
    finishv_k<<<NTGT / 256, 256, 0, stream>>>(c, vv);
  }

  coupling_k<<<8192, 256, 0, stream>>>(K, u, vv, partials);
  finalize_k<<<1, 256, 0, stream>>>(partials, out);
}

// Round 2
// 1059.371 us; speedup vs baseline: 1.0670x; 1.0670x over previous
//
#include <hip/hip_runtime.h>
#include <hip/hip_bf16.h>
#include <math.h>

#define NSRC 8192
#define NTGT 8192
#define DIM 64

// ---------------------------------------------------------------------------
// helpers
// ---------------------------------------------------------------------------
__device__ __forceinline__ float wave_reduce_sum(float x) {
#pragma unroll
  for (int off = 32; off > 0; off >>= 1) x += __shfl_down(x, off, 64);
  return x;
}

__device__ __forceinline__ float bflo(unsigned int u) {  // low bf16 of a u32
  return __uint_as_float(u << 16);
}
__device__ __forceinline__ float bfhi(unsigned int u) {  // high bf16 of a u32
  return __uint_as_float(u & 0xFFFF0000u);
}

// ---------------------------------------------------------------------------
// kernel 1: squared norms of source rows and target rows
// ---------------------------------------------------------------------------
__global__ __launch_bounds__(256) void norms_k(const float* __restrict__ S,
                                               const float* __restrict__ T,
                                               float* __restrict__ s2,
                                               float* __restrict__ t2) {
  int i = blockIdx.x * 256 + threadIdx.x;
  if (i >= NSRC + NTGT) return;
  const float* base = (i < NSRC) ? (S + (size_t)i * DIM)
                                 : (T + (size_t)(i - NSRC) * DIM);
  const float4* p = (const float4*)base;
  float a = 0.f;
#pragma unroll
  for (int k = 0; k < DIM / 4; ++k) {
    float4 v = p[k];
    a += v.x * v.x + v.y * v.y + v.z * v.z + v.w * v.w;
  }
  if (i < NSRC) s2[i] = a;
  else          t2[i - NSRC] = a;
}

// ---------------------------------------------------------------------------
// kernel 2: per-call init. c[]=0 (colsum accumulator), v=1 (initial scaling).
// ---------------------------------------------------------------------------
__global__ __launch_bounds__(256) void init_k(float* __restrict__ c,
                                              float* __restrict__ v_out) {
  int i = blockIdx.x * 256 + threadIdx.x;
  if (i < NTGT) {
    c[i] = 0.f;
    v_out[i] = 1.f;
  }
}

// ---------------------------------------------------------------------------
// kernel 3: build K = exp(-cost/eps) (f32 into coupling region of d_out,
// optional bf16 shadow copy into ws for the matvec passes).
// ---------------------------------------------------------------------------
#define BM 64
#define BN 128
__global__ __launch_bounds__(256) void kbuild_k(const float* __restrict__ S,
                                                const float* __restrict__ T,
                                                const float* __restrict__ s2,
                                                const float* __restrict__ t2,
                                                float* __restrict__ K,
                                                __hip_bfloat16* __restrict__ Kb) {
  __shared__ float sT[BM][68];
  __shared__ float tT[BN][68];
  const int bn = blockIdx.x * BN;
  const int bm = blockIdx.y * BM;
  const int tid = threadIdx.x;

  {
    const float4* sg = (const float4*)(S + (size_t)bm * DIM);
#pragma unroll
    for (int k = 0; k < 4; ++k) {
      int f = tid + 256 * k;
      int row = f >> 4, c4 = f & 15;
      *(float4*)&sT[row][c4 * 4] = sg[f];
    }
    const float4* tg = (const float4*)(T + (size_t)bn * DIM);
#pragma unroll
    for (int k = 0; k < 8; ++k) {
      int f = tid + 256 * k;
      int row = f >> 4, c4 = f & 15;
      *(float4*)&tT[row][c4 * 4] = tg[f];
    }
  }
  __syncthreads();

  const int tx = tid & 15;
  const int ty = tid >> 4;

  float acc[4][8];
#pragma unroll
  for (int a = 0; a < 4; ++a)
#pragma unroll
    for (int b = 0; b < 8; ++b) acc[a][b] = 0.f;

  for (int k = 0; k < DIM; k += 4) {
    float4 sr[4], tr[8];
#pragma unroll
    for (int a = 0; a < 4; ++a) sr[a] = *(float4*)&sT[ty + 16 * a][k];
#pragma unroll
    for (int b = 0; b < 8; ++b) tr[b] = *(float4*)&tT[tx + 16 * b][k];
#pragma unroll
    for (int a = 0; a < 4; ++a)
#pragma unroll
      for (int b = 0; b < 8; ++b) {
        acc[a][b] += sr[a].x * tr[b].x;
        acc[a][b] += sr[a].y * tr[b].y;
        acc[a][b] += sr[a].z * tr[b].z;
        acc[a][b] += sr[a].w * tr[b].w;
      }
  }

#pragma unroll
  for (int a = 0; a < 4; ++a) {
    int gi = bm + ty + 16 * a;
    float s2v = s2[gi];
#pragma unroll
    for (int b = 0; b < 8; ++b) {
      int gj = bn + tx + 16 * b;
      float sq = s2v + t2[gj] - 2.f * acc[a][b];
      float cost = sqrtf(fmaxf(sq, 0.f));
      float kv = __expf(-10.f * cost);  // 1/eps = 10
      size_t off = (size_t)gi * NTGT + gj;
      K[off] = kv;
      if (Kb) Kb[off] = __float2bfloat16(kv);
    }
  }
}

// ---------------------------------------------------------------------------
// kernel 4a: u_i = sw / ((K v)_i + stab). One wave per row. bf16 K.
// ---------------------------------------------------------------------------
__global__ __launch_bounds__(256) void rowsum_bf16_k(const unsigned short* __restrict__ Kb,
                                                     const float* __restrict__ v,
                                                     float* __restrict__ u_out) {
  int row = (blockIdx.x * 256 + threadIdx.x) >> 6;
  int lane = threadIdx.x & 63;
  const uint4* r4 = (const uint4*)(Kb + (size_t)row * NTGT);  // 8 bf16 / uint4
  const float4* v4 = (const float4*)v;
  float a = 0.f;
#pragma unroll 4
  for (int it = lane; it < NTGT / 8; it += 64) {
    uint4 q = r4[it];
    float4 v0 = v4[it * 2];
    float4 v1 = v4[it * 2 + 1];
    a += bflo(q.x) * v0.x + bfhi(q.x) * v0.y;
    a += bflo(q.y) * v0.z + bfhi(q.y) * v0.w;
    a += bflo(q.z) * v1.x + bfhi(q.z) * v1.y;
    a += bflo(q.w) * v1.z + bfhi(q.w) * v1.w;
  }
  a = wave_reduce_sum(a);
  if (lane == 0) u_out[row] = (1.0f / NSRC) / (a + 1e-8f);
}

// kernel 4b: f32 fallback
__global__ __launch_bounds__(256) void rowsum_k(const float* __restrict__ K,
                                                const float* __restrict__ v,
                                                float* __restrict__ u_out) {
  int row = (blockIdx.x * 256 + threadIdx.x) >> 6;
  int lane = threadIdx.x & 63;
  const float4* r4 = (const float4*)(K + (size_t)row * NTGT);
  const float4* v4 = (const float4*)v;
  float a = 0.f;
#pragma unroll 4
  for (int j = lane; j < NTGT / 4; j += 64) {
    float4 k4 = r4[j];
    float4 vv = v4[j];
    a += k4.x * vv.x + k4.y * vv.y + k4.z * vv.z + k4.w * vv.w;
  }
  a = wave_reduce_sum(a);
  if (lane == 0) u_out[row] = (1.0f / NSRC) / (a + 1e-8f);
}

// ---------------------------------------------------------------------------
// kernel 5a: c_j += sum_i K_ij * u_i over a 64-row chunk. bf16 K.
// grid = (4 col-stripes of 2048, 128 row-chunks of 64)
// ---------------------------------------------------------------------------
__global__ __launch_bounds__(256) void colsum_bf16_k(const unsigned short* __restrict__ Kb,
                                                     const float* __restrict__ u,
                                                     float* __restrict__ c) {
  int j = blockIdx.x * 2048 + threadIdx.x * 8;
  int i0 = blockIdx.y * 64;
  float a0 = 0.f, a1 = 0.f, a2 = 0.f, a3 = 0.f;
  float a4 = 0.f, a5 = 0.f, a6 = 0.f, a7 = 0.f;
#pragma unroll 8
  for (int i = i0; i < i0 + 64; ++i) {
    float ui = u[i];
    uint4 q = *(const uint4*)(Kb + (size_t)i * NTGT + j);
    a0 += bflo(q.x) * ui; a1 += bfhi(q.x) * ui;
    a2 += bflo(q.y) * ui; a3 += bfhi(q.y) * ui;
    a4 += bflo(q.z) * ui; a5 += bfhi(q.z) * ui;
    a6 += bflo(q.w) * ui; a7 += bfhi(q.w) * ui;
  }
  atomicAdd(&c[j + 0], a0); atomicAdd(&c[j + 1], a1);
  atomicAdd(&c[j + 2], a2); atomicAdd(&c[j + 3], a3);
  atomicAdd(&c[j + 4], a4); atomicAdd(&c[j + 5], a5);
  atomicAdd(&c[j + 6], a6); atomicAdd(&c[j + 7], a7);
}

// kernel 5b: f32 fallback. grid = (8, 128)
__global__ __launch_bounds__(256) void colsum_k(const float* __restrict__ K,
                                                const float* __restrict__ u,
                                                float* __restrict__ c) {
  int j = blockIdx.x * 1024 + threadIdx.x * 4;
  int i0 = blockIdx.y * 64;
  float a0 = 0.f, a1 = 0.f, a2 = 0.f, a3 = 0.f;
#pragma unroll 8
  for (int i = i0; i < i0 + 64; ++i) {
    float ui = u[i];
    float4 k4 = *(const float4*)(K + (size_t)i * NTGT + j);
    a0 += k4.x * ui; a1 += k4.y * ui; a2 += k4.z * ui; a3 += k4.w * ui;
  }
  atomicAdd(&c[j + 0], a0);
  atomicAdd(&c[j + 1], a1);
  atomicAdd(&c[j + 2], a2);
  atomicAdd(&c[j + 3], a3);
}

// ---------------------------------------------------------------------------
// kernel 6: v_j = tw / (c_j + stab); reset c_j = 0 for next iteration.
// ---------------------------------------------------------------------------
__global__ __launch_bounds__(256) void finishv_k(float* __restrict__ c,
                                                 float* __restrict__ v_out) {
  int j = blockIdx.x * 256 + threadIdx.x;
  v_out[j] = (1.0f / NTGT) / (c[j] + 1e-8f);
  c[j] = 0.f;
}

// ---------------------------------------------------------------------------
// kernel 7: coupling_ij = u_i * K_ij * v_j in place over f32 K;
// accumulate sum(coupling * cost) with cost = -eps*ln(K).
// ---------------------------------------------------------------------------
__global__ __launch_bounds__(256) void coupling_k(float* __restrict__ K,
                                                  const float* __restrict__ u,
                                                  const float* __restrict__ v,
                                                  float* __restrict__ partials) {
  __shared__ float red[4];
  size_t t0 = (size_t)blockIdx.x * 2048 + threadIdx.x;  // float4 index
  float part = 0.f;
#pragma unroll
  for (int s = 0; s < 8; ++s) {
    size_t f4 = t0 + (size_t)s * 256;
    size_t base = f4 * 4;
    int i = (int)(base >> 13);
    int j = (int)(base & 8191);
    float4 k4 = *(float4*)(K + base);
    float ui = u[i];
    float4 vv = *(const float4*)(v + j);
    float c0 = ui * k4.x * vv.x;
    float c1 = ui * k4.y * vv.y;
    float c2 = ui * k4.z * vv.z;
    float c3 = ui * k4.w * vv.w;
    part += c0 * __logf(k4.x) + c1 * __logf(k4.y) +
            c2 * __logf(k4.z) + c3 * __logf(k4.w);
    *(float4*)(K + base) = make_float4(c0, c1, c2, c3);
  }
  part = wave_reduce_sum(part);
  int wid = threadIdx.x >> 6, lane = threadIdx.x & 63;
  if (lane == 0) red[wid] = part;
  __syncthreads();
  if (threadIdx.x == 0)
    partials[blockIdx.x] = red[0] + red[1] + red[2] + red[3];
}

// ---------------------------------------------------------------------------
// kernel 8: dist = -eps * sum(partials) / (ns*nt)
// ---------------------------------------------------------------------------
__global__ __launch_bounds__(256) void finalize_k(const float* __restrict__ partials,
                                                  float* __restrict__ out) {
  __shared__ float red[4];
  float a = 0.f;
  for (int i = threadIdx.x; i < 8192; i += 256) a += partials[i];
  a = wave_reduce_sum(a);
  int wid = threadIdx.x >> 6, lane = threadIdx.x & 63;
  if (lane == 0) red[wid] = a;
  __syncthreads();
  if (threadIdx.x == 0)
    out[0] = (red[0] + red[1] + red[2] + red[3]) *
             (-0.1f / ((float)NSRC * (float)NTGT));
}

// ---------------------------------------------------------------------------
extern "C" void kernel_launch(void* const* d_in, const int* in_sizes, int n_in,
                              void* d_out, int out_size, void* d_ws, size_t ws_size,
                              hipStream_t stream) {
  const float* S = (const float*)d_in[0];
  const float* T = (const float*)d_in[1];
  float* out = (float*)d_out;

  // output layout: [dist(1)][coupling(64M)][u(8192)][v(8192)]
  float* K  = out + 1;
  float* u  = out + 1 + (size_t)NSRC * NTGT;
  float* vv = u + NSRC;

  // ws layout: c[8192] | s2[8192] | t2[8192] | partials[8192]  (= 128 KiB)
  // then (if room) Kb: bf16 copy of K, 128 MiB, 16B-aligned.
  float* wsf      = (float*)d_ws;
  float* c        = wsf;
  float* s2       = wsf + 8192;
  float* t2       = wsf + 16384;
  float* partials = wsf + 24576;

  const size_t KB_BYTES = (size_t)NSRC * NTGT * 2;
  const size_t KB_OFF = 131072;
  bool use_bf16 = ws_size >= KB_OFF + KB_BYTES;
  __hip_bfloat16* Kb = use_bf16
      ? (__hip_bfloat16*)((char*)d_ws + KB_OFF) : (__hip_bfloat16*)nullptr;

  norms_k<<<(NSRC + NTGT + 255) / 256, 256, 0, stream>>>(S, T, s2, t2);
  init_k<<<NTGT / 256, 256, 0, stream>>>(c, vv);
  kbuild_k<<<dim3(NTGT / BN, NSRC / BM), 256, 0, stream>>>(S, T, s2, t2, K, Kb);

  for (int it = 0; it < 10; ++it) {
    if (use_bf16) {
      rowsum_bf16_k<<<NSRC * 64 / 256, 256, 0, stream>>>(
          (const unsigned short*)Kb, vv, u);
      colsum_bf16_k<<<dim3(4, 128), 256, 0, stream>>>(
          (const unsigned short*)Kb, u, c);
    } else {
      rowsum_k<<<NSRC * 64 / 256, 256, 0, stream>>>(K, vv, u);
      colsum_k<<<dim3(8, 128), 256, 0, stream>>>(K, u, c);
    }
    finishv_k<<<NTGT / 256, 256, 0, stream>>>(c, vv);
  }

  coupling_k<<<8192, 256, 0, stream>>>(K, u, vv, partials);
  finalize_k<<<1, 256, 0, stream>>>(partials, out);
}